// Round 2
// baseline (312.155 us; speedup 1.0000x reference)
//
#include <hip/hip_runtime.h>
#include <hip/hip_bf16.h>

typedef __attribute__((ext_vector_type(8))) short bf16x8;
typedef __attribute__((ext_vector_type(4))) float f32x4;
typedef unsigned short u16;
typedef unsigned int u32;

#define B_ 2
#define S_ 2048
#define D_ 1024
#define H_ 16
#define HD_ 64

#define LOG2E 1.44269504088896340736f

__device__ __forceinline__ u16 f2bf(float f) {
    u32 u = __float_as_uint(f);
    u += 0x7FFF + ((u >> 16) & 1);   // RNE
    return (u16)(u >> 16);
}

// ---------------- fp32 -> bf16 elementwise ----------------
__global__ __launch_bounds__(256) void cvt_bf16(const float* __restrict__ in,
                                                u16* __restrict__ out) {
    int i = blockIdx.x * 256 + threadIdx.x;
    float4 v = ((const float4*)in)[i];
    ushort4 o;
    o.x = f2bf(v.x); o.y = f2bf(v.y); o.z = f2bf(v.z); o.w = f2bf(v.w);
    ((ushort4*)out)[i] = o;
}

// ---------------- fp32 [R][C] -> bf16 [C][R] transpose ----------------
__global__ __launch_bounds__(256) void tconv(const float* __restrict__ in,
                                             u16* __restrict__ out, int R, int C) {
    __shared__ float t[32][33];
    int c0 = blockIdx.x * 32, r0 = blockIdx.y * 32;
    int lx = threadIdx.x & 31, ly = threadIdx.x >> 5;
#pragma unroll
    for (int i = 0; i < 4; ++i)
        t[ly + i * 8][lx] = in[(size_t)(r0 + ly + i * 8) * C + c0 + lx];
    __syncthreads();
#pragma unroll
    for (int i = 0; i < 4; ++i)
        out[(size_t)(c0 + ly + i * 8) * R + r0 + lx] = f2bf(t[lx][ly + i * 8]);
}

// ---------------- bf16 GEMM, B transposed ([N][K]) ----------------
// MODE 0: epilogue scatters Q(x0.125*log2e)/K to [bh][s][hd], V TRANSPOSED
//         to [bh][hd][s] (packed ushort4 over s). N=3072.
// MODE 1: epilogue writes fp32 out [M][N] + bias (N=1024)
template <int MODE>
__global__ __launch_bounds__(256) void gemm_bt(
    const u16* __restrict__ A, const u16* __restrict__ Bt,
    const float* __restrict__ bias, int K, int N,
    u16* __restrict__ oQ, u16* __restrict__ oK, u16* __restrict__ oV,
    float* __restrict__ oF) {
    __shared__ u16 Al[128][72];
    __shared__ u16 Bl[128][72];
    const int tid = threadIdx.x;
    const int lane = tid & 63, w = tid >> 6;
    const int wm = w >> 1, wn = w & 1;
    const int l15 = lane & 15, lg = lane >> 4;
    const int m0 = blockIdx.y * 128, n0 = blockIdx.x * 128;
    f32x4 acc[4][4] = {};
    const int srow = tid >> 3, sc8 = (tid & 7) * 8;

    for (int k0 = 0; k0 < K; k0 += 64) {
        __syncthreads();
#pragma unroll
        for (int it = 0; it < 4; ++it) {
            int r = srow + it * 32;
            *(uint4*)&Al[r][sc8] = *(const uint4*)&A[(size_t)(m0 + r) * K + k0 + sc8];
            *(uint4*)&Bl[r][sc8] = *(const uint4*)&Bt[(size_t)(n0 + r) * K + k0 + sc8];
        }
        __syncthreads();
#pragma unroll
        for (int g = 0; g < 2; ++g) {
            bf16x8 af[4], bfr[4];
#pragma unroll
            for (int t = 0; t < 4; ++t) {
                af[t]  = *(const bf16x8*)&Al[wm * 64 + t * 16 + l15][g * 32 + lg * 8];
                bfr[t] = *(const bf16x8*)&Bl[wn * 64 + t * 16 + l15][g * 32 + lg * 8];
            }
#pragma unroll
            for (int mt = 0; mt < 4; ++mt)
#pragma unroll
                for (int nt = 0; nt < 4; ++nt)
                    acc[mt][nt] = __builtin_amdgcn_mfma_f32_16x16x32_bf16(
                        af[mt], bfr[nt], acc[mt][nt], 0, 0, 0);
        }
    }

#pragma unroll
    for (int mt = 0; mt < 4; ++mt) {
#pragma unroll
        for (int nt = 0; nt < 4; ++nt) {
            const int n_g = n0 + wn * 64 + nt * 16 + l15;
            const int m_b = m0 + wm * 64 + mt * 16 + lg * 4;
            const float bs = bias[n_g];
            if (MODE == 0) {
                const int which = n_g >> 10;          // 0=q 1=k 2=v
                const int nn = n_g & 1023;
                const int h = nn >> 6, hd = nn & 63;
                const int bb = m_b >> 11, s = m_b & 2047;
                if (which == 2) {
                    // V transposed: [bh][hd][s], 4 consecutive s -> ushort4
                    ushort4 pv;
                    pv.x = f2bf(acc[mt][nt][0] + bs);
                    pv.y = f2bf(acc[mt][nt][1] + bs);
                    pv.z = f2bf(acc[mt][nt][2] + bs);
                    pv.w = f2bf(acc[mt][nt][3] + bs);
                    *(ushort4*)&oV[((size_t)(bb * H_ + h) * HD_ + hd) * S_ + s] = pv;
                } else {
                    u16* dst = which == 0 ? oQ : oK;
                    const float scale = which == 0 ? (0.125f * LOG2E) : 1.0f;
#pragma unroll
                    for (int r = 0; r < 4; ++r)
                        dst[((size_t)(bb * H_ + h) * S_ + s + r) * HD_ + hd] =
                            f2bf((acc[mt][nt][r] + bs) * scale);
                }
            } else {
#pragma unroll
                for (int r = 0; r < 4; ++r)
                    oF[(size_t)(m_b + r) * N + n_g] = acc[mt][nt][r] + bs;
            }
        }
    }
}

// ---------------- flash attention, causal, barrier-free ----------------
// grid = B*H*(S/64) blocks of 256; each wave owns an independent 16-row
// q-tile. Swapped QK^T (mfma(K,Q) -> S^T): softmax k-axis is lane-local.
// K read [bh][s][hd], V read pre-transposed [bh][hd][s]. No __syncthreads.
__global__ __launch_bounds__(256) void attn2(
    const u16* __restrict__ Q, const u16* __restrict__ Kp,
    const u16* __restrict__ VT, u16* __restrict__ Om) {
    __shared__ u16 Pl[4][16][72];   // per-wave P tile (wave-local, no barrier)
    const int tid = threadIdx.x;
    const int lane = tid & 63, w = tid >> 6;
    const int l15 = lane & 15, lg = lane >> 4;
    // XCD-bijective swizzle (1024 % 8 == 0): each XCD gets 4 whole bh.
    const int hw = blockIdx.x;
    const int bid = (hw & 7) * 128 + (hw >> 3);
    const int bh = bid >> 5, qb = 31 - (bid & 31);   // heavy blocks first
    const int b = bh >> 4, h = bh & 15;
    const int q0 = qb * 64 + w * 16;                 // this wave's q rows
    const size_t baseK = (size_t)bh * (S_ * HD_);
    const size_t baseV = (size_t)bh * (HD_ * S_);

    const bf16x8 qf0 = *(const bf16x8*)&Q[baseK + (size_t)(q0 + l15) * HD_ + lg * 8];
    const bf16x8 qf1 = *(const bf16x8*)&Q[baseK + (size_t)(q0 + l15) * HD_ + 32 + lg * 8];

    f32x4 acc[4] = {};
    float m_run = -1e30f, l_run = 0.0f;
    const int kend = qb * 64;

    for (int kt = 0; kt <= kend; kt += 64) {
        // ---- QK^T swapped: D = S^T, lane holds P[k=nt*16+lg*4+r][q=l15]
        f32x4 sc[4] = {};
#pragma unroll
        for (int nt = 0; nt < 4; ++nt) {
            bf16x8 kb = *(const bf16x8*)&Kp[baseK + (size_t)(kt + nt * 16 + l15) * HD_ + lg * 8];
            sc[nt] = __builtin_amdgcn_mfma_f32_16x16x32_bf16(kb, qf0, sc[nt], 0, 0, 0);
        }
#pragma unroll
        for (int nt = 0; nt < 4; ++nt) {
            bf16x8 kb = *(const bf16x8*)&Kp[baseK + (size_t)(kt + nt * 16 + l15) * HD_ + 32 + lg * 8];
            sc[nt] = __builtin_amdgcn_mfma_f32_16x16x32_bf16(kb, qf1, sc[nt], 0, 0, 0);
        }
        if (kt == kend) {   // diagonal tile: mask k > q
#pragma unroll
            for (int nt = 0; nt < 4; ++nt)
#pragma unroll
                for (int r = 0; r < 4; ++r)
                    if (kt + nt * 16 + lg * 4 + r > q0 + l15) sc[nt][r] = -1e30f;
        }
        // ---- online softmax (scores already in log2 space via Q scale)
        float mx = fmaxf(fmaxf(fmaxf(sc[0][0], sc[0][1]), fmaxf(sc[0][2], sc[0][3])),
                         fmaxf(fmaxf(sc[1][0], sc[1][1]), fmaxf(sc[1][2], sc[1][3])));
        float mx2 = fmaxf(fmaxf(fmaxf(sc[2][0], sc[2][1]), fmaxf(sc[2][2], sc[2][3])),
                          fmaxf(fmaxf(sc[3][0], sc[3][1]), fmaxf(sc[3][2], sc[3][3])));
        mx = fmaxf(mx, mx2);
        mx = fmaxf(mx, __shfl_xor(mx, 16, 64));
        mx = fmaxf(mx, __shfl_xor(mx, 32, 64));
        const float m_new = fmaxf(m_run, mx);
        const float alpha = exp2f(m_run - m_new);
        float ps = 0.0f;
#pragma unroll
        for (int nt = 0; nt < 4; ++nt)
#pragma unroll
            for (int r = 0; r < 4; ++r) {
                float p = exp2f(sc[nt][r] - m_new);
                sc[nt][r] = p;
                ps += p;
            }
        ps += __shfl_xor(ps, 16, 64);
        ps += __shfl_xor(ps, 32, 64);
        l_run = l_run * alpha + ps;
        m_run = m_new;
#pragma unroll
        for (int dt = 0; dt < 4; ++dt) acc[dt] *= alpha;
        // ---- P (S^T layout) -> Pl[q][k] rows, vectorized, wave-local
#pragma unroll
        for (int nt = 0; nt < 4; ++nt) {
            ushort4 pk;
            pk.x = f2bf(sc[nt][0]); pk.y = f2bf(sc[nt][1]);
            pk.z = f2bf(sc[nt][2]); pk.w = f2bf(sc[nt][3]);
            *(ushort4*)&Pl[w][l15][nt * 16 + lg * 4] = pk;
        }
        // ---- PV: D = O^T = mfma(V^T rows, P rows)
#pragma unroll
        for (int g = 0; g < 2; ++g) {
            bf16x8 pb = *(const bf16x8*)&Pl[w][l15][g * 32 + lg * 8];
#pragma unroll
            for (int dt = 0; dt < 4; ++dt) {
                bf16x8 vb = *(const bf16x8*)&VT[baseV + (size_t)(dt * 16 + l15) * S_ + kt + g * 32 + lg * 8];
                acc[dt] = __builtin_amdgcn_mfma_f32_16x16x32_bf16(vb, pb, acc[dt], 0, 0, 0);
            }
        }
    }
    // ---- epilogue: lane holds O[q=q0+l15][d=dt*16+lg*4+r]
    const float rl = 1.0f / l_run;
#pragma unroll
    for (int dt = 0; dt < 4; ++dt) {
        ushort4 ov;
        ov.x = f2bf(acc[dt][0] * rl);
        ov.y = f2bf(acc[dt][1] * rl);
        ov.z = f2bf(acc[dt][2] * rl);
        ov.w = f2bf(acc[dt][3] * rl);
        *(ushort4*)&Om[((size_t)b * S_ + q0 + l15) * D_ + h * HD_ + dt * 16 + lg * 4] = ov;
    }
}

extern "C" void kernel_launch(void* const* d_in, const int* in_sizes, int n_in,
                              void* d_out, int out_size, void* d_ws, size_t ws_size,
                              hipStream_t stream) {
    const float* x      = (const float*)d_in[0];
    const float* w_attn = (const float*)d_in[1];
    const float* b_attn = (const float*)d_in[2];
    const float* w_proj = (const float*)d_in[3];
    const float* b_proj = (const float*)d_in[4];
    float* out = (float*)d_out;

    char* ws = (char*)d_ws;
    const size_t XE = (size_t)B_ * S_ * D_;          // 4194304
    u16* x_bf = (u16*)ws;            ws += XE * 2;   // reused as merged
    u16* waT  = (u16*)ws;            ws += (size_t)3 * D_ * D_ * 2;
    u16* wpT  = (u16*)ws;            ws += (size_t)D_ * D_ * 2;
    u16* Qb   = (u16*)ws;            ws += XE * 2;
    u16* Kb   = (u16*)ws;            ws += XE * 2;
    u16* Vt   = (u16*)ws;            ws += XE * 2;   // [bh][hd][s]
    u16* Mg   = x_bf;                // alias: x_bf dead after GEMM1

    cvt_bf16<<<(int)(XE / 4 / 256), 256, 0, stream>>>(x, x_bf);
    tconv<<<dim3(3 * D_ / 32, D_ / 32), 256, 0, stream>>>(w_attn, waT, D_, 3 * D_);
    tconv<<<dim3(D_ / 32, D_ / 32), 256, 0, stream>>>(w_proj, wpT, D_, D_);

    gemm_bt<0><<<dim3(3 * D_ / 128, B_ * S_ / 128), 256, 0, stream>>>(
        x_bf, waT, b_attn, D_, 3 * D_, Qb, Kb, Vt, nullptr);

    attn2<<<B_ * H_ * (S_ / 64), 256, 0, stream>>>(Qb, Kb, Vt, Mg);

    gemm_bt<1><<<dim3(D_ / 128, B_ * S_ / 128), 256, 0, stream>>>(
        Mg, wpT, b_proj, D_, D_, nullptr, nullptr, nullptr, out);
}

// Round 3
// 164.583 us; speedup vs baseline: 1.8966x; 1.8966x over previous
//
#include <hip/hip_runtime.h>
#include <hip/hip_bf16.h>

typedef __attribute__((ext_vector_type(8))) short bf16x8;
typedef __attribute__((ext_vector_type(4))) float f32x4;
typedef unsigned short u16;
typedef unsigned int u32;

#define B_ 2
#define S_ 2048
#define D_ 1024
#define H_ 16
#define HD_ 64

#define LOG2E 1.44269504088896340736f

__device__ __forceinline__ u16 f2bf(float f) {
    u32 u = __float_as_uint(f);
    u += 0x7FFF + ((u >> 16) & 1);   // RNE
    return (u16)(u >> 16);
}

// async global->LDS, 16B per lane. lds_base is wave-uniform; lane l lands at
// lds_base + l*16 bytes. gsrc is per-lane.
__device__ __forceinline__ void gload16(const u16* gsrc, u16* lds_base) {
    __builtin_amdgcn_global_load_lds(
        (const __attribute__((address_space(1))) void*)gsrc,
        (__attribute__((address_space(3))) void*)lds_base, 16, 0, 0);
}

// swizzled read from a [rows][64] u16 tile: elem col c, row r -> c ^ ((r&7)*8)
__device__ __forceinline__ bf16x8 rd64(const u16* lds, int row, int c) {
    return *(const bf16x8*)&lds[row * 64 + (c ^ ((row & 7) * 8))];
}

// ---------------- fp32 -> bf16 elementwise ----------------
__global__ __launch_bounds__(256) void cvt_bf16(const float* __restrict__ in,
                                                u16* __restrict__ out) {
    int i = blockIdx.x * 256 + threadIdx.x;
    float4 v = ((const float4*)in)[i];
    ushort4 o;
    o.x = f2bf(v.x); o.y = f2bf(v.y); o.z = f2bf(v.z); o.w = f2bf(v.w);
    ((ushort4*)out)[i] = o;
}

// ---------------- fp32 [R][C] -> bf16 [C][R] transpose ----------------
__global__ __launch_bounds__(256) void tconv(const float* __restrict__ in,
                                             u16* __restrict__ out, int R, int C) {
    __shared__ float t[32][33];
    int c0 = blockIdx.x * 32, r0 = blockIdx.y * 32;
    int lx = threadIdx.x & 31, ly = threadIdx.x >> 5;
#pragma unroll
    for (int i = 0; i < 4; ++i)
        t[ly + i * 8][lx] = in[(size_t)(r0 + ly + i * 8) * C + c0 + lx];
    __syncthreads();
#pragma unroll
    for (int i = 0; i < 4; ++i)
        out[(size_t)(c0 + ly + i * 8) * R + r0 + lx] = f2bf(t[lx][ly + i * 8]);
}

// ---------------- bf16 GEMM, B transposed ([N][K]), m97-style staging ------
// MODE 0: epilogue scatters Q(x0.125*log2e)/K to [bh][s][hd], V TRANSPOSED
//         to [bh][hd][s] (packed ushort4 over s). N=3072.
// MODE 1: epilogue writes fp32 out [M][N] + bias (N=1024)
template <int MODE>
__global__ __launch_bounds__(256) void gemm_bt(
    const u16* __restrict__ A, const u16* __restrict__ Bt,
    const float* __restrict__ bias, int K, int N,
    u16* __restrict__ oQ, u16* __restrict__ oK, u16* __restrict__ oV,
    float* __restrict__ oF) {
    __shared__ u16 Al[128 * 64];
    __shared__ u16 Bl[128 * 64];
    const int tid = threadIdx.x;
    const int lane = tid & 63, w = tid >> 6;
    const int wm = w >> 1, wn = w & 1;
    const int l15 = lane & 15, lg = lane >> 4;
    const int m0 = blockIdx.y * 128, n0 = blockIdx.x * 128;
    f32x4 acc[4][4] = {};
    const int lrow = lane >> 3;                       // 0..7 within 8-row seg
    const int csrc = ((lane & 7) * 8) ^ ((lrow & 7) * 8);  // swizzled src col

    for (int k0 = 0; k0 < K; k0 += 64) {
        __syncthreads();                               // prior reads complete
        const u16* ga = A + (size_t)m0 * K + k0;
        const u16* gb = Bt + (size_t)n0 * K + k0;
#pragma unroll
        for (int i = 0; i < 4; ++i) {
            const int j = w * 4 + i;                   // 16 segs of 8 rows
            const int row = j * 8 + lrow;
            gload16(ga + (size_t)row * K + csrc, &Al[j * 512]);
            gload16(gb + (size_t)row * K + csrc, &Bl[j * 512]);
        }
        __syncthreads();                               // staging drained
#pragma unroll
        for (int g = 0; g < 2; ++g) {
            bf16x8 af[4], bfr[4];
#pragma unroll
            for (int t = 0; t < 4; ++t) {
                af[t]  = rd64(Al, wm * 64 + t * 16 + l15, g * 32 + lg * 8);
                bfr[t] = rd64(Bl, wn * 64 + t * 16 + l15, g * 32 + lg * 8);
            }
#pragma unroll
            for (int mt = 0; mt < 4; ++mt)
#pragma unroll
                for (int nt = 0; nt < 4; ++nt)
                    acc[mt][nt] = __builtin_amdgcn_mfma_f32_16x16x32_bf16(
                        af[mt], bfr[nt], acc[mt][nt], 0, 0, 0);
        }
    }

#pragma unroll
    for (int mt = 0; mt < 4; ++mt) {
#pragma unroll
        for (int nt = 0; nt < 4; ++nt) {
            const int n_g = n0 + wn * 64 + nt * 16 + l15;
            const int m_b = m0 + wm * 64 + mt * 16 + lg * 4;
            const float bs = bias[n_g];
            if (MODE == 0) {
                const int which = n_g >> 10;          // 0=q 1=k 2=v
                const int nn = n_g & 1023;
                const int h = nn >> 6, hd = nn & 63;
                const int bb = m_b >> 11, s = m_b & 2047;
                if (which == 2) {
                    ushort4 pv;
                    pv.x = f2bf(acc[mt][nt][0] + bs);
                    pv.y = f2bf(acc[mt][nt][1] + bs);
                    pv.z = f2bf(acc[mt][nt][2] + bs);
                    pv.w = f2bf(acc[mt][nt][3] + bs);
                    *(ushort4*)&oV[((size_t)(bb * H_ + h) * HD_ + hd) * S_ + s] = pv;
                } else {
                    u16* dst = which == 0 ? oQ : oK;
                    const float scale = which == 0 ? (0.125f * LOG2E) : 1.0f;
#pragma unroll
                    for (int r = 0; r < 4; ++r)
                        dst[((size_t)(bb * H_ + h) * S_ + s + r) * HD_ + hd] =
                            f2bf((acc[mt][nt][r] + bs) * scale);
                }
            } else {
#pragma unroll
                for (int r = 0; r < 4; ++r)
                    oF[(size_t)(m_b + r) * N + n_g] = acc[mt][nt][r] + bs;
            }
        }
    }
}

// ---------------- flash attention, causal, 2-phase dbuf ----------------
// grid = B*H*(S/64) blocks of 256; wave w owns q rows qb*64+w*16..+15.
// Swapped QK^T (mfma(K,Q) -> S^T): softmax k-axis lane-local. K [bh][s][hd],
// V pre-transposed [bh][hd][s]. K/V tiles double-buffered in LDS via
// global_load_lds; ONE __syncthreads per iter (stage for t+1 in flight
// during compute of t). XOR-swizzled LDS (inverse swizzle on global src).
__global__ __launch_bounds__(256) void attn3(
    const u16* __restrict__ Q, const u16* __restrict__ Kp,
    const u16* __restrict__ VT, u16* __restrict__ Om) {
    __shared__ u16 Kl[2][64 * 64];
    __shared__ u16 Vl[2][64 * 64];
    __shared__ u16 Pl[4][16 * 64];
    const int tid = threadIdx.x;
    const int lane = tid & 63, w = tid >> 6;
    const int l15 = lane & 15, lg = lane >> 4;
    // XCD-bijective swizzle (1024 % 8 == 0): each XCD gets 4 whole bh.
    const int hw = blockIdx.x;
    const int bid = (hw & 7) * 128 + (hw >> 3);
    const int bh = bid >> 5, qb = 31 - (bid & 31);   // heavy blocks first
    const int b = bh >> 4, h = bh & 15;
    const int q0 = qb * 64 + w * 16;
    const size_t baseK = (size_t)bh * (S_ * HD_);
    const size_t baseV = (size_t)bh * (HD_ * S_);
    const u16* gk = Kp + baseK;                       // rows s, stride 64
    const u16* gv = VT + baseV;                       // rows d, stride 2048

    const bf16x8 qf0 = *(const bf16x8*)&Q[baseK + (size_t)(q0 + l15) * HD_ + lg * 8];
    const bf16x8 qf1 = *(const bf16x8*)&Q[baseK + (size_t)(q0 + l15) * HD_ + 32 + lg * 8];

    const int lrow = lane >> 3;
    const int csrc = ((lane & 7) * 8) ^ ((lrow & 7) * 8);

    f32x4 acc[4] = {};
    float m_run = -1e30f, l_run = 0.0f;
    const int kend = qb * 64;

    // prologue: stage tile kt=0 into buf 0 (each wave: segs w*2, w*2+1)
#pragma unroll
    for (int i = 0; i < 2; ++i) {
        const int j = w * 2 + i;
        const int row = j * 8 + lrow;
        gload16(gk + (size_t)row * 64 + csrc, &Kl[0][j * 512]);
        gload16(gv + (size_t)row * 2048 + csrc, &Vl[0][j * 512]);
    }

    for (int kt = 0; kt <= kend; kt += 64) {
        const int cur = (kt >> 6) & 1;
        __syncthreads();                   // drain stage of buf[cur]
        if (kt < kend) {                   // issue stage of next tile (async)
#pragma unroll
            for (int i = 0; i < 2; ++i) {
                const int j = w * 2 + i;
                const int row = j * 8 + lrow;
                gload16(gk + (size_t)(kt + 64 + row) * 64 + csrc, &Kl[cur ^ 1][j * 512]);
                gload16(gv + (size_t)row * 2048 + (kt + 64) + csrc, &Vl[cur ^ 1][j * 512]);
            }
        }
        // ---- QK^T swapped: lane holds P[k=nt*16+lg*4+r][q=l15]
        f32x4 sc[4] = {};
#pragma unroll
        for (int nt = 0; nt < 4; ++nt) {
            bf16x8 kb = rd64(Kl[cur], nt * 16 + l15, lg * 8);
            sc[nt] = __builtin_amdgcn_mfma_f32_16x16x32_bf16(kb, qf0, sc[nt], 0, 0, 0);
        }
#pragma unroll
        for (int nt = 0; nt < 4; ++nt) {
            bf16x8 kb = rd64(Kl[cur], nt * 16 + l15, 32 + lg * 8);
            sc[nt] = __builtin_amdgcn_mfma_f32_16x16x32_bf16(kb, qf1, sc[nt], 0, 0, 0);
        }
        if (kt == kend) {   // diagonal tile: mask k > q
#pragma unroll
            for (int nt = 0; nt < 4; ++nt)
#pragma unroll
                for (int r = 0; r < 4; ++r)
                    if (kt + nt * 16 + lg * 4 + r > q0 + l15) sc[nt][r] = -1e30f;
        }
        // ---- online softmax (log2 space; Q pre-scaled by 0.125*log2e)
        float mx = fmaxf(fmaxf(fmaxf(sc[0][0], sc[0][1]), fmaxf(sc[0][2], sc[0][3])),
                         fmaxf(fmaxf(sc[1][0], sc[1][1]), fmaxf(sc[1][2], sc[1][3])));
        float mx2 = fmaxf(fmaxf(fmaxf(sc[2][0], sc[2][1]), fmaxf(sc[2][2], sc[2][3])),
                          fmaxf(fmaxf(sc[3][0], sc[3][1]), fmaxf(sc[3][2], sc[3][3])));
        mx = fmaxf(mx, mx2);
        mx = fmaxf(mx, __shfl_xor(mx, 16, 64));
        mx = fmaxf(mx, __shfl_xor(mx, 32, 64));
        const float m_new = fmaxf(m_run, mx);
        const float alpha = exp2f(m_run - m_new);
        float ps = 0.0f;
#pragma unroll
        for (int nt = 0; nt < 4; ++nt)
#pragma unroll
            for (int r = 0; r < 4; ++r) {
                float p = exp2f(sc[nt][r] - m_new);
                sc[nt][r] = p;
                ps += p;
            }
        ps += __shfl_xor(ps, 16, 64);
        ps += __shfl_xor(ps, 32, 64);
        l_run = l_run * alpha + ps;
        m_run = m_new;
#pragma unroll
        for (int dt = 0; dt < 4; ++dt) acc[dt] *= alpha;
        // ---- P (S^T) -> Pl rows [q][k], swizzled, wave-local
#pragma unroll
        for (int nt = 0; nt < 4; ++nt) {
            ushort4 pk;
            pk.x = f2bf(sc[nt][0]); pk.y = f2bf(sc[nt][1]);
            pk.z = f2bf(sc[nt][2]); pk.w = f2bf(sc[nt][3]);
            const int c = (nt * 16 + lg * 4) ^ ((l15 & 7) * 8);
            *(ushort4*)&Pl[w][l15 * 64 + c] = pk;
        }
        // ---- PV: O^T = mfma(V^T rows, P rows)
#pragma unroll
        for (int g = 0; g < 2; ++g) {
            bf16x8 pb = rd64(Pl[w], l15, g * 32 + lg * 8);
#pragma unroll
            for (int dt = 0; dt < 4; ++dt) {
                bf16x8 vb = rd64(Vl[cur], dt * 16 + l15, g * 32 + lg * 8);
                acc[dt] = __builtin_amdgcn_mfma_f32_16x16x32_bf16(vb, pb, acc[dt], 0, 0, 0);
            }
        }
    }
    // ---- epilogue: lane holds O[q=q0+l15][d=dt*16+lg*4+r]
    const float rl = 1.0f / l_run;
#pragma unroll
    for (int dt = 0; dt < 4; ++dt) {
        ushort4 ov;
        ov.x = f2bf(acc[dt][0] * rl);
        ov.y = f2bf(acc[dt][1] * rl);
        ov.z = f2bf(acc[dt][2] * rl);
        ov.w = f2bf(acc[dt][3] * rl);
        *(ushort4*)&Om[((size_t)b * S_ + q0 + l15) * D_ + h * HD_ + dt * 16 + lg * 4] = ov;
    }
}

extern "C" void kernel_launch(void* const* d_in, const int* in_sizes, int n_in,
                              void* d_out, int out_size, void* d_ws, size_t ws_size,
                              hipStream_t stream) {
    const float* x      = (const float*)d_in[0];
    const float* w_attn = (const float*)d_in[1];
    const float* b_attn = (const float*)d_in[2];
    const float* w_proj = (const float*)d_in[3];
    const float* b_proj = (const float*)d_in[4];
    float* out = (float*)d_out;

    char* ws = (char*)d_ws;
    const size_t XE = (size_t)B_ * S_ * D_;          // 4194304
    u16* x_bf = (u16*)ws;            ws += XE * 2;   // reused as merged
    u16* waT  = (u16*)ws;            ws += (size_t)3 * D_ * D_ * 2;
    u16* wpT  = (u16*)ws;            ws += (size_t)D_ * D_ * 2;
    u16* Qb   = (u16*)ws;            ws += XE * 2;
    u16* Kb   = (u16*)ws;            ws += XE * 2;
    u16* Vt   = (u16*)ws;            ws += XE * 2;   // [bh][hd][s]
    u16* Mg   = x_bf;                // alias: x_bf dead after GEMM1

    cvt_bf16<<<(int)(XE / 4 / 256), 256, 0, stream>>>(x, x_bf);
    tconv<<<dim3(3 * D_ / 32, D_ / 32), 256, 0, stream>>>(w_attn, waT, D_, 3 * D_);
    tconv<<<dim3(D_ / 32, D_ / 32), 256, 0, stream>>>(w_proj, wpT, D_, D_);

    gemm_bt<0><<<dim3(3 * D_ / 128, B_ * S_ / 128), 256, 0, stream>>>(
        x_bf, waT, b_attn, D_, 3 * D_, Qb, Kb, Vt, nullptr);

    attn3<<<B_ * H_ * (S_ / 64), 256, 0, stream>>>(Qb, Kb, Vt, Mg);

    gemm_bt<1><<<dim3(D_ / 128, B_ * S_ / 128), 256, 0, stream>>>(
        Mg, wpT, b_proj, D_, D_, nullptr, nullptr, nullptr, out);
}

// Round 4
// 124.438 us; speedup vs baseline: 2.5085x; 1.3226x over previous
//
#include <hip/hip_runtime.h>
#include <hip/hip_bf16.h>

typedef __attribute__((ext_vector_type(8))) short bf16x8;
typedef __attribute__((ext_vector_type(4))) float f32x4;
typedef unsigned short u16;
typedef unsigned int u32;

#define B_ 2
#define S_ 2048
#define D_ 1024
#define H_ 16
#define HD_ 64

#define LOG2E 1.44269504088896340736f

__device__ __forceinline__ u16 f2bf(float f) {
    __hip_bfloat16 h = __float2bfloat16(f);   // RNE, native cvt on gfx950
    u16 r;
    __builtin_memcpy(&r, &h, 2);
    return r;
}

// raw v_exp_f32: exp2(x). Handles x=-1e30 -> 0. 1 instruction.
__device__ __forceinline__ float ex2(float x) {
    float r;
    asm("v_exp_f32 %0, %1" : "=v"(r) : "v"(x));
    return r;
}

// async global->LDS, 16B per lane. lds_base wave-uniform; lane l -> +l*16B.
__device__ __forceinline__ void gload16(const u16* gsrc, u16* lds_base) {
    __builtin_amdgcn_global_load_lds(
        (const __attribute__((address_space(1))) void*)gsrc,
        (__attribute__((address_space(3))) void*)lds_base, 16, 0, 0);
}

// swizzled read from a [rows][64] u16 tile: elem col c, row r -> c ^ ((r&7)*8)
__device__ __forceinline__ bf16x8 rd64(const u16* lds, int row, int c) {
    return *(const bf16x8*)&lds[row * 64 + (c ^ ((row & 7) * 8))];
}

// ---------------- fp32 -> bf16 elementwise ----------------
__global__ __launch_bounds__(256) void cvt_bf16(const float* __restrict__ in,
                                                u16* __restrict__ out) {
    int i = blockIdx.x * 256 + threadIdx.x;
    float4 v = ((const float4*)in)[i];
    ushort4 o;
    o.x = f2bf(v.x); o.y = f2bf(v.y); o.z = f2bf(v.z); o.w = f2bf(v.w);
    ((ushort4*)out)[i] = o;
}

// ---------------- fp32 [R][C] -> bf16 [C][R] transpose ----------------
__global__ __launch_bounds__(256) void tconv(const float* __restrict__ in,
                                             u16* __restrict__ out, int R, int C) {
    __shared__ float t[32][33];
    int c0 = blockIdx.x * 32, r0 = blockIdx.y * 32;
    int lx = threadIdx.x & 31, ly = threadIdx.x >> 5;
#pragma unroll
    for (int i = 0; i < 4; ++i)
        t[ly + i * 8][lx] = in[(size_t)(r0 + ly + i * 8) * C + c0 + lx];
    __syncthreads();
#pragma unroll
    for (int i = 0; i < 4; ++i)
        out[(size_t)(c0 + ly + i * 8) * R + r0 + lx] = f2bf(t[lx][ly + i * 8]);
}

// ---------------- bf16 GEMM, B transposed ([N][K]), m97-style staging ------
// MODE 0: epilogue scatters Q(x0.125*log2e)/K to [bh][s][hd], V TRANSPOSED
//         to [bh][hd][s] (packed ushort4 over s). N=3072.
// MODE 1: epilogue writes fp32 out [M][N] + bias (N=1024)
template <int MODE>
__global__ __launch_bounds__(256) void gemm_bt(
    const u16* __restrict__ A, const u16* __restrict__ Bt,
    const float* __restrict__ bias, int K, int N,
    u16* __restrict__ oQ, u16* __restrict__ oK, u16* __restrict__ oV,
    float* __restrict__ oF) {
    __shared__ u16 Al[128 * 64];
    __shared__ u16 Bl[128 * 64];
    const int tid = threadIdx.x;
    const int lane = tid & 63, w = tid >> 6;
    const int wm = w >> 1, wn = w & 1;
    const int l15 = lane & 15, lg = lane >> 4;
    // XCD-chunked swizzle: each XCD gets a contiguous row-major chunk.
    const int lin = blockIdx.y * gridDim.x + blockIdx.x;
    const int per = (gridDim.x * gridDim.y) >> 3;   // grids are %8==0
    const int nl = (lin & 7) * per + (lin >> 3);
    const int m0 = (nl / gridDim.x) * 128, n0 = (nl % gridDim.x) * 128;
    f32x4 acc[4][4] = {};
    const int lrow = lane >> 3;                       // 0..7 within 8-row seg
    const int csrc = ((lane & 7) * 8) ^ ((lrow & 7) * 8);  // swizzled src col

    for (int k0 = 0; k0 < K; k0 += 64) {
        __syncthreads();                               // prior reads complete
        const u16* ga = A + (size_t)m0 * K + k0;
        const u16* gb = Bt + (size_t)n0 * K + k0;
#pragma unroll
        for (int i = 0; i < 4; ++i) {
            const int j = w * 4 + i;                   // 16 segs of 8 rows
            const int row = j * 8 + lrow;
            gload16(ga + (size_t)row * K + csrc, &Al[j * 512]);
            gload16(gb + (size_t)row * K + csrc, &Bl[j * 512]);
        }
        __syncthreads();                               // staging drained
#pragma unroll
        for (int g = 0; g < 2; ++g) {
            bf16x8 af[4], bfr[4];
#pragma unroll
            for (int t = 0; t < 4; ++t) {
                af[t]  = rd64(Al, wm * 64 + t * 16 + l15, g * 32 + lg * 8);
                bfr[t] = rd64(Bl, wn * 64 + t * 16 + l15, g * 32 + lg * 8);
            }
#pragma unroll
            for (int mt = 0; mt < 4; ++mt)
#pragma unroll
                for (int nt = 0; nt < 4; ++nt)
                    acc[mt][nt] = __builtin_amdgcn_mfma_f32_16x16x32_bf16(
                        af[mt], bfr[nt], acc[mt][nt], 0, 0, 0);
        }
    }

#pragma unroll
    for (int mt = 0; mt < 4; ++mt) {
#pragma unroll
        for (int nt = 0; nt < 4; ++nt) {
            const int n_g = n0 + wn * 64 + nt * 16 + l15;
            const int m_b = m0 + wm * 64 + mt * 16 + lg * 4;
            const float bs = bias[n_g];
            if (MODE == 0) {
                const int which = n_g >> 10;          // 0=q 1=k 2=v
                const int nn = n_g & 1023;
                const int h = nn >> 6, hd = nn & 63;
                const int bb = m_b >> 11, s = m_b & 2047;
                if (which == 2) {
                    ushort4 pv;
                    pv.x = f2bf(acc[mt][nt][0] + bs);
                    pv.y = f2bf(acc[mt][nt][1] + bs);
                    pv.z = f2bf(acc[mt][nt][2] + bs);
                    pv.w = f2bf(acc[mt][nt][3] + bs);
                    *(ushort4*)&oV[((size_t)(bb * H_ + h) * HD_ + hd) * S_ + s] = pv;
                } else {
                    u16* dst = which == 0 ? oQ : oK;
                    const float scale = which == 0 ? (0.125f * LOG2E) : 1.0f;
#pragma unroll
                    for (int r = 0; r < 4; ++r)
                        dst[((size_t)(bb * H_ + h) * S_ + s + r) * HD_ + hd] =
                            f2bf((acc[mt][nt][r] + bs) * scale);
                }
            } else {
#pragma unroll
                for (int r = 0; r < 4; ++r)
                    oF[(size_t)(m_b + r) * N + n_g] = acc[mt][nt][r] + bs;
            }
        }
    }
}

// ---------------- flash attention, causal, paired q-tiles ----------------
// grid = B*H*16 = 512 blocks of 256. Block (bh,p) handles q-tiles qb=31-p
// then qb=p: uniform 33 k-iterations per block (no tail). Swapped QK^T
// (softmax k-axis lane-local, per-lane partial l), defer-max rescale,
// raw v_exp, hoisted LDS offsets, dbuf K/V via global_load_lds.
__global__ __launch_bounds__(256) void attn4(
    const u16* __restrict__ Q, const u16* __restrict__ Kp,
    const u16* __restrict__ VT, u16* __restrict__ Om) {
    __shared__ u16 Kl[2][64 * 64];
    __shared__ u16 Vl[2][64 * 64];
    __shared__ u16 Pl[4][16 * 64];
    const int tid = threadIdx.x;
    const int lane = tid & 63, w = tid >> 6;
    const int l15 = lane & 15, lg = lane >> 4;
    const int hw = blockIdx.x;                    // 512 blocks
    const int bid = (hw & 7) * 64 + (hw >> 3);    // XCD-contiguous (512%8==0)
    const int bh = bid >> 4, p = bid & 15;
    const int b = bh >> 4, h = bh & 15;
    const size_t baseK = (size_t)bh * (S_ * HD_);
    const u16* gk = Kp + baseK;                   // [s][64]
    const u16* gv = VT + (size_t)bh * (HD_ * S_); // [64][2048]

    // staging: wave w fills segs {2w, 2w+1} (rows w*16+lrow, +8)
    const int lrow = lane >> 3;
    const int csrc = ((lane & 7) * 8) ^ ((lrow & 7) * 8);
    const int r0s = w * 16 + lrow, r1s = r0s + 8;
    const u16* gkA = gk + r0s * HD_ + csrc;
    const u16* gkB = gk + r1s * HD_ + csrc;
    const u16* gvA = gv + r0s * S_ + csrc;
    const u16* gvB = gv + r1s * S_ + csrc;
    u16* ldsKA = &Kl[0][w * 1024];
    u16* ldsKB = &Kl[0][w * 1024 + 512];
    u16* ldsVA = &Vl[0][w * 1024];
    u16* ldsVB = &Vl[0][w * 1024 + 512];

    // hoisted LDS read offsets (bytes)
    const int sw = (l15 & 7) * 8;
    const int rb = l15 * 128;
    const int ro0 = rb + 2 * ((lg * 8) ^ sw);
    const int ro1 = rb + 2 * ((32 + lg * 8) ^ sw);
    const char* kbase = (const char*)&Kl[0][0];
    const char* vbase = (const char*)&Vl[0][0];
    char* plw = (char*)&Pl[w][0];
    int pw0 = rb + 2 * ((0 * 16 + lg * 4) ^ sw);
    int pw1 = rb + 2 * ((1 * 16 + lg * 4) ^ sw);
    int pw2 = rb + 2 * ((2 * 16 + lg * 4) ^ sw);
    int pw3 = rb + 2 * ((3 * 16 + lg * 4) ^ sw);

#pragma unroll 1
    for (int t = 0; t < 2; ++t) {
        const int qb = t == 0 ? (31 - p) : p;
        const int q0 = qb * 64 + w * 16;
        const int kend = qb * 64;

        const bf16x8 qf0 = *(const bf16x8*)&Q[baseK + (size_t)(q0 + l15) * HD_ + lg * 8];
        const bf16x8 qf1 = *(const bf16x8*)&Q[baseK + (size_t)(q0 + l15) * HD_ + 32 + lg * 8];

        f32x4 acc[4] = {};
        float m_run = -1e30f, l_run = 0.0f;

        __syncthreads();                 // prev tile's reads done
        // prologue: stage kt=0 into buf 0
        gload16(gkA, ldsKA);
        gload16(gkB, ldsKB);
        gload16(gvA, ldsVA);
        gload16(gvB, ldsVB);

        for (int kt = 0; kt <= kend; kt += 64) {
            const int cur = (kt >> 6) & 1;
            const int bo = cur * 8192;   // buffer byte offset
            __syncthreads();             // stage of buf[cur] drained
            if (kt < kend) {             // stage next tile into buf[cur^1]
                const int bo1 = (cur ^ 1) * 4096;  // elem offset
                gload16(gkA + (kt + 64) * HD_, ldsKA + bo1);
                gload16(gkB + (kt + 64) * HD_, ldsKB + bo1);
                gload16(gvA + (kt + 64), ldsVA + bo1);
                gload16(gvB + (kt + 64), ldsVB + bo1);
            }
            // ---- QK^T swapped: sc[nt][r] = S^T[k=kt+nt*16+lg*4+r][q=q0+l15]
            const char* kb = kbase + bo;
            f32x4 sc[4] = {};
#pragma unroll
            for (int nt = 0; nt < 4; ++nt) {
                bf16x8 kf = *(const bf16x8*)(kb + nt * 2048 + ro0);
                sc[nt] = __builtin_amdgcn_mfma_f32_16x16x32_bf16(kf, qf0, sc[nt], 0, 0, 0);
            }
#pragma unroll
            for (int nt = 0; nt < 4; ++nt) {
                bf16x8 kf = *(const bf16x8*)(kb + nt * 2048 + ro1);
                sc[nt] = __builtin_amdgcn_mfma_f32_16x16x32_bf16(kf, qf1, sc[nt], 0, 0, 0);
            }
            if (kt == kend) {            // diagonal: mask k > q
#pragma unroll
                for (int nt = 0; nt < 4; ++nt)
#pragma unroll
                    for (int r = 0; r < 4; ++r)
                        if (nt * 16 + lg * 4 + r > w * 16 + l15) sc[nt][r] = -1e30f;
            }
            // ---- online softmax (log2 domain), per-row max across lanes
            float m0 = fmaxf(fmaxf(sc[0][0], sc[0][1]), fmaxf(sc[0][2], sc[0][3]));
            float m1 = fmaxf(fmaxf(sc[1][0], sc[1][1]), fmaxf(sc[1][2], sc[1][3]));
            float m2 = fmaxf(fmaxf(sc[2][0], sc[2][1]), fmaxf(sc[2][2], sc[2][3]));
            float m3 = fmaxf(fmaxf(sc[3][0], sc[3][1]), fmaxf(sc[3][2], sc[3][3]));
            float mx = fmaxf(fmaxf(m0, m1), fmaxf(m2, m3));
            mx = fmaxf(mx, __shfl_xor(mx, 16, 64));
            mx = fmaxf(mx, __shfl_xor(mx, 32, 64));
            if (!__all(mx <= m_run + 8.0f)) {     // defer-max (THR=8 log2)
                const float m_new = fmaxf(m_run, mx);
                const float al = ex2(m_run - m_new);
                l_run *= al;
                acc[0] *= al; acc[1] *= al; acc[2] *= al; acc[3] *= al;
                m_run = m_new;
            }
            float psn[4];
#pragma unroll
            for (int nt = 0; nt < 4; ++nt) {
                float a = ex2(sc[nt][0] - m_run);
                float c = ex2(sc[nt][1] - m_run);
                float d = ex2(sc[nt][2] - m_run);
                float e = ex2(sc[nt][3] - m_run);
                sc[nt][0] = a; sc[nt][1] = c; sc[nt][2] = d; sc[nt][3] = e;
                psn[nt] = (a + c) + (d + e);
            }
            l_run += (psn[0] + psn[1]) + (psn[2] + psn[3]);
            // ---- P -> Pl (wave-local, swizzled)
            {
                ushort4 pk;
                pk.x = f2bf(sc[0][0]); pk.y = f2bf(sc[0][1]);
                pk.z = f2bf(sc[0][2]); pk.w = f2bf(sc[0][3]);
                *(ushort4*)(plw + pw0) = pk;
                pk.x = f2bf(sc[1][0]); pk.y = f2bf(sc[1][1]);
                pk.z = f2bf(sc[1][2]); pk.w = f2bf(sc[1][3]);
                *(ushort4*)(plw + pw1) = pk;
                pk.x = f2bf(sc[2][0]); pk.y = f2bf(sc[2][1]);
                pk.z = f2bf(sc[2][2]); pk.w = f2bf(sc[2][3]);
                *(ushort4*)(plw + pw2) = pk;
                pk.x = f2bf(sc[3][0]); pk.y = f2bf(sc[3][1]);
                pk.z = f2bf(sc[3][2]); pk.w = f2bf(sc[3][3]);
                *(ushort4*)(plw + pw3) = pk;
            }
            // ---- PV: O^T = mfma(V^T rows, P rows)
            const char* vb = vbase + bo;
            {
                bf16x8 pb0 = *(const bf16x8*)(plw + ro0);
#pragma unroll
                for (int dt = 0; dt < 4; ++dt) {
                    bf16x8 vf = *(const bf16x8*)(vb + dt * 2048 + ro0);
                    acc[dt] = __builtin_amdgcn_mfma_f32_16x16x32_bf16(vf, pb0, acc[dt], 0, 0, 0);
                }
                bf16x8 pb1 = *(const bf16x8*)(plw + ro1);
#pragma unroll
                for (int dt = 0; dt < 4; ++dt) {
                    bf16x8 vf = *(const bf16x8*)(vb + dt * 2048 + ro1);
                    acc[dt] = __builtin_amdgcn_mfma_f32_16x16x32_bf16(vf, pb1, acc[dt], 0, 0, 0);
                }
            }
        }
        // ---- epilogue: lane holds O^T[d=dt*16+lg*4+r][q=q0+l15]
        float lt = l_run + __shfl_xor(l_run, 16, 64);
        lt = lt + __shfl_xor(lt, 32, 64);
        const float rl = 1.0f / lt;
#pragma unroll
        for (int dt = 0; dt < 4; ++dt) {
            ushort4 ov;
            ov.x = f2bf(acc[dt][0] * rl);
            ov.y = f2bf(acc[dt][1] * rl);
            ov.z = f2bf(acc[dt][2] * rl);
            ov.w = f2bf(acc[dt][3] * rl);
            *(ushort4*)&Om[((size_t)b * S_ + q0 + l15) * D_ + h * HD_ + dt * 16 + lg * 4] = ov;
        }
    }
}

extern "C" void kernel_launch(void* const* d_in, const int* in_sizes, int n_in,
                              void* d_out, int out_size, void* d_ws, size_t ws_size,
                              hipStream_t stream) {
    const float* x      = (const float*)d_in[0];
    const float* w_attn = (const float*)d_in[1];
    const float* b_attn = (const float*)d_in[2];
    const float* w_proj = (const float*)d_in[3];
    const float* b_proj = (const float*)d_in[4];
    float* out = (float*)d_out;

    char* ws = (char*)d_ws;
    const size_t XE = (size_t)B_ * S_ * D_;          // 4194304
    u16* x_bf = (u16*)ws;            ws += XE * 2;   // reused as merged
    u16* waT  = (u16*)ws;            ws += (size_t)3 * D_ * D_ * 2;
    u16* wpT  = (u16*)ws;            ws += (size_t)D_ * D_ * 2;
    u16* Qb   = (u16*)ws;            ws += XE * 2;
    u16* Kb   = (u16*)ws;            ws += XE * 2;
    u16* Vt   = (u16*)ws;            ws += XE * 2;   // [bh][hd][s]
    u16* Mg   = x_bf;                // alias: x_bf dead after GEMM1

    cvt_bf16<<<(int)(XE / 4 / 256), 256, 0, stream>>>(x, x_bf);
    tconv<<<dim3(3 * D_ / 32, D_ / 32), 256, 0, stream>>>(w_attn, waT, D_, 3 * D_);
    tconv<<<dim3(D_ / 32, D_ / 32), 256, 0, stream>>>(w_proj, wpT, D_, D_);

    gemm_bt<0><<<dim3(3 * D_ / 128, B_ * S_ / 128), 256, 0, stream>>>(
        x_bf, waT, b_attn, D_, 3 * D_, Qb, Kb, Vt, nullptr);

    attn4<<<B_ * H_ * 16, 256, 0, stream>>>(Qb, Kb, Vt, Mg);

    gemm_bt<1><<<dim3(D_ / 128, B_ * S_ / 128), 256, 0, stream>>>(
        Mg, wpT, b_proj, D_, D_, nullptr, nullptr, nullptr, out);
}